// Round 11
// baseline (451.762 us; speedup 1.0000x reference)
//
#include <hip/hip_runtime.h>
#include <math.h>

#define NN 50000
#define NE 800000
#define NR 3125               // row-groups of 16 (50000/16)

typedef __attribute__((ext_vector_type(8))) short short8;
typedef __attribute__((ext_vector_type(8))) unsigned short ushort8;
typedef __attribute__((ext_vector_type(4))) float f32x4;

// fragment-major addressing for 64-wide node tensors:
//   addr(n, c) = (n>>4)*1024 + (c>>3)*128 + (n&15)*8 + (c&7)
#define FM(n, c) ((((n) >> 4) << 10) + (((c) >> 3) << 7) + (((n) & 15) << 3) + ((c) & 7))

// workspace layout (offsets in 4-byte words)
#define OFF_DEG    0          // float[NN] -> dinv
#define OFF_CNT    50000      // int[NN]
#define OFF_ROWPTR 100000     // int[NN+1]
#define OFF_BSUM   200008     // int[64]
#define OFF_WB     200072     // ushort[192*512] = 49152 words (fragment-major Wb2)
#define OFF_BIAS   249224     // float[256]
#define OFF_ELIST  249480     // uint[NE]
#define OFF_XB     1849480    // ushort[NR*1024] = 1.6M words each (fragment-major)
#define OFF_HB     3449480
#define OFF_T1X    5049480
#define OFF_T1H    6649480
#define OFF_T2X    8249480
#define OFF_T2H    9849480
// overlays (consumed before their hosts are written):
#define OFF_HISTP  5049480    // ushort[128][50000] over T1X+T1H
#define OFF_COLEXC 8249480    // ushort[128][50000] over T2X+T2H
#define OFF_DEGP   1849480    // float[64][50000] over XB+HB

#define DCH    128
#define DCHUNK 6250
#define DITER  25
#define SCH    64
#define SCHUNK 12500
#define SITER  49

__device__ inline unsigned short f2bf(float f) {
  union { float f; unsigned u; } v; v.f = f;
  unsigned u = v.u;
  return (unsigned short)((u + 0x7FFFu + ((u >> 16) & 1u)) >> 16);
}
__device__ inline float bf2f(unsigned short u) {
  return __uint_as_float(((unsigned)u) << 16);
}
__device__ inline float sigm(float x) { return 1.f / (1.f + __expf(-x)); }
__device__ inline float tanh_(float x) { return 1.f - 2.f / (__expf(2.f * x) + 1.f); }

// fused histogram/degree, 512 blocks @ 50KB LDS
__global__ __launch_bounds__(256) void k_hd(
    const int* __restrict__ src, const int* __restrict__ dst,
    const float* __restrict__ w,
    unsigned short* __restrict__ histp, float* __restrict__ degp) {
  __shared__ unsigned lds[12500];
  const int t = threadIdx.x;
  const int bid = blockIdx.x;
  if (bid < 256) {
    const int c = bid >> 1, half = bid & 1, lo = half * 25000;
    for (int i = t; i < 12500; i += 256) lds[i] = 0u;
    __syncthreads();
    const int e0 = c * DCHUNK;
    for (int it = 0; it < DITER; ++it) {
      int o = it * 256 + t;
      if (o < DCHUNK) {
        int d = dst[e0 + o] - lo;
        if ((unsigned)d < 25000u)
          atomicAdd(&lds[d >> 1], (d & 1) ? 65536u : 1u);
      }
    }
    __syncthreads();
    unsigned* hw = (unsigned*)(histp + c * 50000 + lo);
    for (int i = t; i < 12500; i += 256) hw[i] = lds[i];
  } else {
    const int idx = bid - 256;
    const int c = idx >> 2, q = idx & 3, lo = q * 12500;
    float* ldsf = (float*)lds;
    for (int i = t; i < 12500; i += 256) ldsf[i] = 0.f;
    __syncthreads();
    const int e0 = c * SCHUNK;
    for (int it = 0; it < SITER; ++it) {
      int o = it * 256 + t;
      if (o < SCHUNK) {
        int s = src[e0 + o] - lo;
        if ((unsigned)s < 12500u) atomicAdd(&ldsf[s], w[e0 + o]);
      }
    }
    __syncthreads();
    float* dw = degp + c * 50000 + lo;
    for (int i = t; i < 12500; i += 256) dw[i] = ldsf[i];
  }
}

// per-bin column sums: cnt + colexc + dinv
__global__ void k_col(const unsigned short* __restrict__ histp,
                      unsigned short* __restrict__ colexc,
                      const float* __restrict__ degp,
                      int* __restrict__ cnt, float* __restrict__ dinv) {
  int bin = blockIdx.x * 256 + threadIdx.x;
  if (bin >= NN) return;
  int acc = 0;
#pragma unroll 8
  for (int b = 0; b < DCH; ++b) {
    unsigned short c = histp[b * 50000 + bin];
    colexc[b * 50000 + bin] = (unsigned short)acc;
    acc += c;
  }
  cnt[bin] = acc;
  float dacc = 0.f;
#pragma unroll 8
  for (int b = 0; b < SCH; ++b) dacc += degp[b * 50000 + bin];
  dinv[bin] = (dacc > 0.f) ? rsqrtf(dacc) : 0.f;
}

// cvt X,H -> bf16 fragment-major (8 elems/thread) + Wb2 fragment-major + bias
#define CBLK 1563
#define WBLK 48    // 12288 threads, one ushort8 word each
__global__ __launch_bounds__(256) void k_cw(
    const float* __restrict__ X, const float* __restrict__ H,
    unsigned short* __restrict__ Xb, unsigned short* __restrict__ Hb,
    const float* __restrict__ Wx, const float* __restrict__ Wh,
    const float* __restrict__ bx, const float* __restrict__ bh,
    const float* __restrict__ bg,
    unsigned short* __restrict__ Wb2, float* __restrict__ bias) {
  const int bid = blockIdx.x;
  const int t = threadIdx.x;
  if (bid < CBLK) {
    int gid = bid * 256 + t;
    if (gid >= NN * 8) return;
    int n = gid >> 3, cg = gid & 7;
    int i = n * 64 + cg * 8;
    float4 x0 = *(const float4*)&X[i];
    float4 x1 = *(const float4*)&X[i + 4];
    float4 h0 = *(const float4*)&H[i];
    float4 h1 = *(const float4*)&H[i + 4];
    ushort8 xb, hb;
    xb[0] = f2bf(x0.x); xb[1] = f2bf(x0.y); xb[2] = f2bf(x0.z); xb[3] = f2bf(x0.w);
    xb[4] = f2bf(x1.x); xb[5] = f2bf(x1.y); xb[6] = f2bf(x1.z); xb[7] = f2bf(x1.w);
    hb[0] = f2bf(h0.x); hb[1] = f2bf(h0.y); hb[2] = f2bf(h0.z); hb[3] = f2bf(h0.w);
    hb[4] = f2bf(h1.x); hb[5] = f2bf(h1.y); hb[6] = f2bf(h1.z); hb[7] = f2bf(h1.w);
    int o = FM(n, cg * 8);
    *(ushort8*)&Xb[o] = xb;
    *(ushort8*)&Hb[o] = hb;
  } else {
    int idx = (bid - CBLK) * 256 + t;   // one ushort8 word of Wb2
    if (idx < 256) bias[idx] = bx[idx] + bh[idx] + bg[idx];
    if (idx >= 192 * 64) return;
    int word = idx >> 6, l = idx & 63;
    int cw = word & 3;
    int gk = word >> 2;          // g*12 + kc
    int g = gk / 12, kc = gk - g * 12;
    int col = cw * 16 + (l & 15);          // col within gate
    int scheb = kc >> 1;                    // 0..5
    int seg = scheb;                        // seg index 0..5 -> Wx k0..2 / Wh k0..2
    int kbase = (kc & 1) * 32 + (l >> 4) * 8;  // k within 64-wide seg
    const float* Wsel = (seg < 3) ? Wx : Wh;
    int sch = (seg < 3) ? seg : seg - 3;
    ushort8 o8;
#pragma unroll
    for (int j = 0; j < 8; ++j) {
      float v = Wsel[((g * 3 + sch) * 64 + kbase + j) * 64 + col];
      o8[j] = f2bf(v);
    }
    *(ushort8*)&Wb2[idx * 8] = o8;
  }
}

// scans
__global__ __launch_bounds__(1024) void k_scanA(const int* __restrict__ cnt,
                                                int* __restrict__ rowptr,
                                                int* __restrict__ bsum) {
  __shared__ int wsum[16];
  int t = threadIdx.x, lane = t & 63, w = t >> 6;
  int i = blockIdx.x * 1024 + t;
  int v = (i < NN) ? cnt[i] : 0;
  int val = v;
#pragma unroll
  for (int off = 1; off < 64; off <<= 1) {
    int u = __shfl_up(val, off, 64);
    if (lane >= off) val += u;
  }
  if (lane == 63) wsum[w] = val;
  __syncthreads();
  if (w == 0) {
    int s = (lane < 16) ? wsum[lane] : 0;
#pragma unroll
    for (int off = 1; off < 16; off <<= 1) {
      int u = __shfl_up(s, off, 64);
      if (lane >= off) s += u;
    }
    if (lane < 16) wsum[lane] = s;
  }
  __syncthreads();
  int incl = ((w > 0) ? wsum[w - 1] : 0) + val;
  if (i < NN) rowptr[i + 1] = incl;
  if (t == 1023) bsum[blockIdx.x] = incl;
}

__global__ void k_scanB(int* __restrict__ bsum, int* __restrict__ rowptr, int nblk) {
  int lane = threadIdx.x;
  int v = (lane < nblk) ? bsum[lane] : 0;
  int val = v;
#pragma unroll
  for (int off = 1; off < 64; off <<= 1) {
    int u = __shfl_up(val, off, 64);
    if (lane >= off) val += u;
  }
  if (lane < nblk) bsum[lane] = val - v;
  if (lane == 0) rowptr[0] = 0;
}

__global__ __launch_bounds__(1024) void k_scanC(int* __restrict__ rowptr,
                                                const int* __restrict__ bsum) {
  int i = blockIdx.x * 1024 + threadIdx.x;
  if (i >= NN) return;
  rowptr[i + 1] += bsum[blockIdx.x];
}

// scatter, 256 blocks @ 50KB
__global__ __launch_bounds__(256) void k_scat(
    const int* __restrict__ src, const int* __restrict__ dst,
    const float* __restrict__ w, const float* __restrict__ dinv,
    const int* __restrict__ rowptr, const unsigned short* __restrict__ colexc,
    unsigned* __restrict__ elist) {
  __shared__ unsigned lds[12500];
  const int t = threadIdx.x, bid = blockIdx.x;
  const int c = bid >> 1, half = bid & 1, lo = half * 25000;
  for (int i = t; i < 12500; i += 256) lds[i] = 0u;
  __syncthreads();
  const int e0 = c * DCHUNK;
  for (int it = 0; it < DITER; ++it) {
    int o = it * 256 + t;
    if (o < DCHUNK) {
      int e = e0 + o;
      int d = dst[e];
      int dr = d - lo;
      if ((unsigned)dr < 25000u) {
        int s = src[e];
        float nm = -dinv[s] * w[e] * dinv[d];
        unsigned old = atomicAdd(&lds[dr >> 1], (dr & 1) ? 65536u : 1u);
        int rank = (dr & 1) ? (int)(old >> 16) : (int)(old & 0xffffu);
        int pos = rowptr[d] + (int)colexc[c * 50000 + d] + rank;
        elist[pos] = (((unsigned)f2bf(nm)) << 16) | (unsigned)s;
      }
    }
  }
}

// prop: wave per node; lane = (edge-slot es, ch-group cg); fragment-major I/O
__global__ __launch_bounds__(256) void k_prop(
    const int* __restrict__ rowptr, const unsigned* __restrict__ elist,
    const unsigned short* __restrict__ inX, const unsigned short* __restrict__ inH,
    unsigned short* __restrict__ outX, unsigned short* __restrict__ outH,
    const unsigned short* __restrict__ baseX, const unsigned short* __restrict__ baseH,
    int mode) {
  const int n = blockIdx.x * 4 + (threadIdx.x >> 6);
  const int l = threadIdx.x & 63;
  const int es = l >> 3;
  const int cg = l & 7;
  if (n >= NN) return;
  const int beg = rowptr[n], end = rowptr[n + 1];
  float ax[8], ah[8];
#pragma unroll
  for (int j = 0; j < 8; ++j) { ax[j] = 0.f; ah[j] = 0.f; }
  for (int i0 = beg; i0 < end; i0 += 8) {
    int ie = i0 + es;
    unsigned u = (ie < end) ? elist[ie] : 0u;
    int s = (int)(u & 0xffffu);
    float nm = __uint_as_float(u & 0xffff0000u);
    int ga = FM(s, cg * 8);
    ushort8 xv = *(const ushort8*)&inX[ga];
    ushort8 hv = *(const ushort8*)&inH[ga];
#pragma unroll
    for (int j = 0; j < 8; ++j) {
      ax[j] += nm * bf2f(xv[j]);
      ah[j] += nm * bf2f(hv[j]);
    }
  }
#pragma unroll
  for (int mask = 8; mask <= 32; mask <<= 1) {
#pragma unroll
    for (int j = 0; j < 8; ++j) {
      ax[j] += __shfl_xor(ax[j], mask, 64);
      ah[j] += __shfl_xor(ah[j], mask, 64);
    }
  }
  if (es == 0) {
    const int o = FM(n, cg * 8);
    ushort8 ox, oh;
    if (mode) {
      ushort8 bx8 = *(const ushort8*)&baseX[o];
      ushort8 bh8 = *(const ushort8*)&baseH[o];
#pragma unroll
      for (int j = 0; j < 8; ++j) {
        ox[j] = f2bf(2.f * ax[j] - bf2f(bx8[j]));
        oh[j] = f2bf(2.f * ah[j] - bf2f(bh8[j]));
      }
    } else {
#pragma unroll
      for (int j = 0; j < 8; ++j) { ox[j] = f2bf(ax[j]); oh[j] = f2bf(ah[j]); }
    }
    *(ushort8*)&outX[o] = ox;
    *(ushort8*)&outH[o] = oh;
  }
}

// MFMA gates v9: fragment-major operands -> every load is one contiguous 1KB
// wave transaction. Block = 64 rows (4 row-groups), wave = 16-col group, all 4
// gates in-register, no LDS, no barriers.
__global__ __launch_bounds__(256, 3) void k_gates(
    const unsigned short* __restrict__ Xb, const unsigned short* __restrict__ Hb,
    const unsigned short* __restrict__ T1X, const unsigned short* __restrict__ T1H,
    const unsigned short* __restrict__ T2X, const unsigned short* __restrict__ T2H,
    const unsigned short* __restrict__ Wb2, const float* __restrict__ C,
    const float* __restrict__ bias, const float* __restrict__ wc,
    float* __restrict__ out) {
  const int t = threadIdx.x;
  const int cw = t >> 6;
  const int l = t & 63;
  const int base = blockIdx.x * 64;
  const int R0 = blockIdx.x * 4;
  const int lr = l & 15;

  f32x4 acc[4][4];              // [gate][row-group]
#pragma unroll
  for (int g = 0; g < 4; ++g)
#pragma unroll
    for (int rb = 0; rb < 4; ++rb) acc[g][rb] = (f32x4){0.f, 0.f, 0.f, 0.f};

  int Rc[4];
#pragma unroll
  for (int rb = 0; rb < 4; ++rb) {
    int R = R0 + rb;
    Rc[rb] = (R < NR) ? R : NR - 1;
  }

  const unsigned short* segp[6] = {Xb, T1X, T2X, Hb, T1H, T2H};
#pragma unroll
  for (int kc = 0; kc < 12; ++kc) {
    const unsigned short* sp = segp[kc >> 1];
    const int ho = (kc & 1) * 512 + l * 8;
    short8 a[4];
#pragma unroll
    for (int rb = 0; rb < 4; ++rb)
      a[rb] = *(const short8*)&sp[(Rc[rb] << 10) + ho];
#pragma unroll
    for (int g = 0; g < 4; ++g) {
      short8 b = *(const short8*)&Wb2[(((g * 12 + kc) * 4 + cw) << 9) + l * 8];
#pragma unroll
      for (int rb = 0; rb < 4; ++rb)
        acc[g][rb] = __builtin_amdgcn_mfma_f32_16x16x32_bf16(a[rb], b, acc[g][rb], 0, 0, 0);
    }
  }

  const int cc = cw * 16 + lr;
  const float bI = bias[cc],       bF = bias[64 + cc];
  const float bT = bias[128 + cc], bO = bias[192 + cc];
  const float wI = wc[cc], wF = wc[64 + cc], wO = wc[128 + cc];
#pragma unroll
  for (int rb = 0; rb < 4; ++rb) {
#pragma unroll
    for (int q = 0; q < 4; ++q) {
      int n = base + rb * 16 + (l >> 4) * 4 + q;
      if (n >= NN) continue;
      float cv = C[n * 64 + cc];
      float pI = acc[0][rb][q] + bI + wI * cv;
      float pF = acc[1][rb][q] + bF + wF * cv;
      float pT = acc[2][rb][q] + bT;
      float I = sigm(pI);
      float F = sigm(pF);
      float T = tanh_(pT);
      float Cn = F * cv + I * T;
      float pO = acc[3][rb][q] + bO + wO * Cn;
      float O = sigm(pO);
      out[n * 64 + cc] = O * tanh_(Cn);
      out[NN * 64 + n * 64 + cc] = Cn;
    }
  }
}

extern "C" void kernel_launch(void* const* d_in, const int* in_sizes, int n_in,
                              void* d_out, int out_size, void* d_ws, size_t ws_size,
                              hipStream_t stream) {
  const float* X  = (const float*)d_in[0];
  const int*   ei = (const int*)d_in[1];
  const float* ew = (const float*)d_in[2];
  const float* H  = (const float*)d_in[3];
  const float* C  = (const float*)d_in[4];
  const float* Wx = (const float*)d_in[5];
  const float* bx = (const float*)d_in[6];
  const float* Wh = (const float*)d_in[7];
  const float* bh = (const float*)d_in[8];
  const float* wc = (const float*)d_in[9];
  const float* bg = (const float*)d_in[10];
  float* out = (float*)d_out;
  float* ws = (float*)d_ws;

  const int* src = ei;
  const int* dst = ei + NE;
  float* dinv = ws + OFF_DEG;
  int* cnt = (int*)(ws + OFF_CNT);
  int* rowptr = (int*)(ws + OFF_ROWPTR);
  int* bsum = (int*)(ws + OFF_BSUM);
  unsigned short* Wb2 = (unsigned short*)(ws + OFF_WB);
  float* bias = ws + OFF_BIAS;
  unsigned* elist = (unsigned*)(ws + OFF_ELIST);
  unsigned short* histp = (unsigned short*)(ws + OFF_HISTP);
  unsigned short* colexc = (unsigned short*)(ws + OFF_COLEXC);
  float* degp = ws + OFF_DEGP;
  unsigned short* Xb  = (unsigned short*)(ws + OFF_XB);
  unsigned short* Hb  = (unsigned short*)(ws + OFF_HB);
  unsigned short* T1X = (unsigned short*)(ws + OFF_T1X);
  unsigned short* T1H = (unsigned short*)(ws + OFF_T1H);
  unsigned short* T2X = (unsigned short*)(ws + OFF_T2X);
  unsigned short* T2H = (unsigned short*)(ws + OFF_T2H);

  const int NBLK = (NN + 1023) / 1024;  // 49

  k_hd<<<512, 256, 0, stream>>>(src, dst, ew, histp, degp);
  k_col<<<(NN + 255) / 256, 256, 0, stream>>>(histp, colexc, degp, cnt, dinv);
  k_cw<<<CBLK + WBLK, 256, 0, stream>>>(X, H, Xb, Hb, Wx, Wh, bx, bh, bg, Wb2, bias);
  k_scanA<<<NBLK, 1024, 0, stream>>>(cnt, rowptr, bsum);
  k_scanB<<<1, 64, 0, stream>>>(bsum, rowptr, NBLK);
  k_scanC<<<NBLK, 1024, 0, stream>>>(rowptr, bsum);
  k_scat<<<256, 256, 0, stream>>>(src, dst, ew, dinv, rowptr, colexc, elist);
  k_prop<<<NN / 4, 256, 0, stream>>>(rowptr, elist, Xb, Hb, T1X, T1H,
                                     nullptr, nullptr, 0);
  k_prop<<<NN / 4, 256, 0, stream>>>(rowptr, elist, T1X, T1H, T2X, T2H,
                                     Xb, Hb, 1);
  k_gates<<<(NN + 63) / 64, 256, 0, stream>>>(Xb, Hb, T1X, T1H, T2X, T2H,
                                              Wb2, C, bias, wc, out);
}

// Round 12
// 220.556 us; speedup vs baseline: 2.0483x; 2.0483x over previous
//
#include <hip/hip_runtime.h>
#include <math.h>

#define NN 50000
#define NE 800000

typedef __attribute__((ext_vector_type(8))) short short8;
typedef __attribute__((ext_vector_type(8))) unsigned short ushort8;
typedef __attribute__((ext_vector_type(4))) float f32x4;

// workspace layout (offsets in 4-byte words) -- node-major tensors
#define OFF_DEG    0          // float[NN] -> dinv
#define OFF_CNT    50000      // int[NN]
#define OFF_ROWPTR 100000     // int[NN+1]
#define OFF_BSUM   200008     // int[64]
#define OFF_WB     200072     // ushort[192*512] fragment-major Wb2 (49152 words)
#define OFF_BIAS   249224     // float[256]
#define OFF_ELIST  249480     // uint[NE]
#define OFF_XB     1849480    // ushort[NN*64] node-major, 1.6M words each
#define OFF_HB     3449480
#define OFF_T1X    5049480
#define OFF_T1H    6649480
#define OFF_T2X    8249480
#define OFF_T2H    9849480
// overlays (consumed before their hosts are written):
#define OFF_HISTP  5049480    // ushort[128][50000] over T1X+T1H
#define OFF_COLEXC 8249480    // ushort[128][50000] over T2X+T2H
#define OFF_DEGP   1849480    // float[64][50000] over XB+HB

#define DCH    128
#define DCHUNK 6250
#define DITER  25
#define SCH    64
#define SCHUNK 12500
#define SITER  49

__device__ inline unsigned short f2bf(float f) {
  union { float f; unsigned u; } v; v.f = f;
  unsigned u = v.u;
  return (unsigned short)((u + 0x7FFFu + ((u >> 16) & 1u)) >> 16);
}
__device__ inline float bf2f(unsigned short u) {
  return __uint_as_float(((unsigned)u) << 16);
}
__device__ inline float sigm(float x) { return 1.f / (1.f + __expf(-x)); }
__device__ inline float tanh_(float x) { return 1.f - 2.f / (__expf(2.f * x) + 1.f); }

// fused histogram/degree, 512 blocks @ 50KB LDS
__global__ __launch_bounds__(256) void k_hd(
    const int* __restrict__ src, const int* __restrict__ dst,
    const float* __restrict__ w,
    unsigned short* __restrict__ histp, float* __restrict__ degp) {
  __shared__ unsigned lds[12500];
  const int t = threadIdx.x;
  const int bid = blockIdx.x;
  if (bid < 256) {
    const int c = bid >> 1, half = bid & 1, lo = half * 25000;
    for (int i = t; i < 12500; i += 256) lds[i] = 0u;
    __syncthreads();
    const int e0 = c * DCHUNK;
    for (int it = 0; it < DITER; ++it) {
      int o = it * 256 + t;
      if (o < DCHUNK) {
        int d = dst[e0 + o] - lo;
        if ((unsigned)d < 25000u)
          atomicAdd(&lds[d >> 1], (d & 1) ? 65536u : 1u);
      }
    }
    __syncthreads();
    unsigned* hw = (unsigned*)(histp + c * 50000 + lo);
    for (int i = t; i < 12500; i += 256) hw[i] = lds[i];
  } else {
    const int idx = bid - 256;
    const int c = idx >> 2, q = idx & 3, lo = q * 12500;
    float* ldsf = (float*)lds;
    for (int i = t; i < 12500; i += 256) ldsf[i] = 0.f;
    __syncthreads();
    const int e0 = c * SCHUNK;
    for (int it = 0; it < SITER; ++it) {
      int o = it * 256 + t;
      if (o < SCHUNK) {
        int s = src[e0 + o] - lo;
        if ((unsigned)s < 12500u) atomicAdd(&ldsf[s], w[e0 + o]);
      }
    }
    __syncthreads();
    float* dw = degp + c * 50000 + lo;
    for (int i = t; i < 12500; i += 256) dw[i] = ldsf[i];
  }
}

// per-bin column sums: cnt + colexc + dinv
__global__ void k_col(const unsigned short* __restrict__ histp,
                      unsigned short* __restrict__ colexc,
                      const float* __restrict__ degp,
                      int* __restrict__ cnt, float* __restrict__ dinv) {
  int bin = blockIdx.x * 256 + threadIdx.x;
  if (bin >= NN) return;
  int acc = 0;
#pragma unroll 8
  for (int b = 0; b < DCH; ++b) {
    unsigned short c = histp[b * 50000 + bin];
    colexc[b * 50000 + bin] = (unsigned short)acc;
    acc += c;
  }
  cnt[bin] = acc;
  float dacc = 0.f;
#pragma unroll 8
  for (int b = 0; b < SCH; ++b) dacc += degp[b * 50000 + bin];
  dinv[bin] = (dacc > 0.f) ? rsqrtf(dacc) : 0.f;
}

// cvt X,H -> bf16 node-major (8/thread) + Wb2 fragment-major + bias
#define CBLK 1563
#define WBLK 48    // 12288 threads, one ushort8 word of Wb2 each
__global__ __launch_bounds__(256) void k_cw(
    const float* __restrict__ X, const float* __restrict__ H,
    unsigned short* __restrict__ Xb, unsigned short* __restrict__ Hb,
    const float* __restrict__ Wx, const float* __restrict__ Wh,
    const float* __restrict__ bx, const float* __restrict__ bh,
    const float* __restrict__ bg,
    unsigned short* __restrict__ Wb2, float* __restrict__ bias) {
  const int bid = blockIdx.x;
  const int t = threadIdx.x;
  if (bid < CBLK) {
    int i = (bid * 256 + t) * 8;
    if (i >= NN * 64) return;
    float4 x0 = *(const float4*)&X[i];
    float4 x1 = *(const float4*)&X[i + 4];
    float4 h0 = *(const float4*)&H[i];
    float4 h1 = *(const float4*)&H[i + 4];
    ushort8 xb, hb;
    xb[0] = f2bf(x0.x); xb[1] = f2bf(x0.y); xb[2] = f2bf(x0.z); xb[3] = f2bf(x0.w);
    xb[4] = f2bf(x1.x); xb[5] = f2bf(x1.y); xb[6] = f2bf(x1.z); xb[7] = f2bf(x1.w);
    hb[0] = f2bf(h0.x); hb[1] = f2bf(h0.y); hb[2] = f2bf(h0.z); hb[3] = f2bf(h0.w);
    hb[4] = f2bf(h1.x); hb[5] = f2bf(h1.y); hb[6] = f2bf(h1.z); hb[7] = f2bf(h1.w);
    *(ushort8*)&Xb[i] = xb;
    *(ushort8*)&Hb[i] = hb;
  } else {
    int idx = (bid - CBLK) * 256 + t;   // one ushort8 word of Wb2
    if (idx < 256) bias[idx] = bx[idx] + bh[idx] + bg[idx];
    if (idx >= 192 * 64) return;
    int word = idx >> 6, l = idx & 63;
    int cw = word & 3;
    int gk = word >> 2;                 // g*12 + kc
    int g = gk / 12, kc = gk - g * 12;
    int col = cw * 16 + (l & 15);
    int seg = kc >> 1;
    int kbase = (kc & 1) * 32 + (l >> 4) * 8;
    const float* Wsel = (seg < 3) ? Wx : Wh;
    int sch = (seg < 3) ? seg : seg - 3;
    ushort8 o8;
#pragma unroll
    for (int j = 0; j < 8; ++j) {
      float v = Wsel[((g * 3 + sch) * 64 + kbase + j) * 64 + col];
      o8[j] = f2bf(v);
    }
    *(ushort8*)&Wb2[idx * 8] = o8;
  }
}

// scans
__global__ __launch_bounds__(1024) void k_scanA(const int* __restrict__ cnt,
                                                int* __restrict__ rowptr,
                                                int* __restrict__ bsum) {
  __shared__ int wsum[16];
  int t = threadIdx.x, lane = t & 63, w = t >> 6;
  int i = blockIdx.x * 1024 + t;
  int v = (i < NN) ? cnt[i] : 0;
  int val = v;
#pragma unroll
  for (int off = 1; off < 64; off <<= 1) {
    int u = __shfl_up(val, off, 64);
    if (lane >= off) val += u;
  }
  if (lane == 63) wsum[w] = val;
  __syncthreads();
  if (w == 0) {
    int s = (lane < 16) ? wsum[lane] : 0;
#pragma unroll
    for (int off = 1; off < 16; off <<= 1) {
      int u = __shfl_up(s, off, 64);
      if (lane >= off) s += u;
    }
    if (lane < 16) wsum[lane] = s;
  }
  __syncthreads();
  int incl = ((w > 0) ? wsum[w - 1] : 0) + val;
  if (i < NN) rowptr[i + 1] = incl;
  if (t == 1023) bsum[blockIdx.x] = incl;
}

__global__ void k_scanB(int* __restrict__ bsum, int* __restrict__ rowptr, int nblk) {
  int lane = threadIdx.x;
  int v = (lane < nblk) ? bsum[lane] : 0;
  int val = v;
#pragma unroll
  for (int off = 1; off < 64; off <<= 1) {
    int u = __shfl_up(val, off, 64);
    if (lane >= off) val += u;
  }
  if (lane < nblk) bsum[lane] = val - v;
  if (lane == 0) rowptr[0] = 0;
}

__global__ __launch_bounds__(1024) void k_scanC(int* __restrict__ rowptr,
                                                const int* __restrict__ bsum) {
  int i = blockIdx.x * 1024 + threadIdx.x;
  if (i >= NN) return;
  rowptr[i + 1] += bsum[blockIdx.x];
}

// scatter, 256 blocks @ 50KB
__global__ __launch_bounds__(256) void k_scat(
    const int* __restrict__ src, const int* __restrict__ dst,
    const float* __restrict__ w, const float* __restrict__ dinv,
    const int* __restrict__ rowptr, const unsigned short* __restrict__ colexc,
    unsigned* __restrict__ elist) {
  __shared__ unsigned lds[12500];
  const int t = threadIdx.x, bid = blockIdx.x;
  const int c = bid >> 1, half = bid & 1, lo = half * 25000;
  for (int i = t; i < 12500; i += 256) lds[i] = 0u;
  __syncthreads();
  const int e0 = c * DCHUNK;
  for (int it = 0; it < DITER; ++it) {
    int o = it * 256 + t;
    if (o < DCHUNK) {
      int e = e0 + o;
      int d = dst[e];
      int dr = d - lo;
      if ((unsigned)dr < 25000u) {
        int s = src[e];
        float nm = -dinv[s] * w[e] * dinv[d];
        unsigned old = atomicAdd(&lds[dr >> 1], (dr & 1) ? 65536u : 1u);
        int rank = (dr & 1) ? (int)(old >> 16) : (int)(old & 0xffffu);
        int pos = rowptr[d] + (int)colexc[c * 50000 + d] + rank;
        elist[pos] = (((unsigned)f2bf(nm)) << 16) | (unsigned)s;
      }
    }
  }
}

// prop (node-major): wave per node; lane = (edge-slot es 0-7, ch-group cg 0-7)
__global__ __launch_bounds__(256) void k_prop(
    const int* __restrict__ rowptr, const unsigned* __restrict__ elist,
    const unsigned short* __restrict__ inX, const unsigned short* __restrict__ inH,
    unsigned short* __restrict__ outX, unsigned short* __restrict__ outH,
    const unsigned short* __restrict__ baseX, const unsigned short* __restrict__ baseH,
    int mode) {
  const int n = blockIdx.x * 4 + (threadIdx.x >> 6);
  const int l = threadIdx.x & 63;
  const int es = l >> 3;
  const int cg = l & 7;
  if (n >= NN) return;
  const int beg = rowptr[n], end = rowptr[n + 1];
  float ax[8], ah[8];
#pragma unroll
  for (int j = 0; j < 8; ++j) { ax[j] = 0.f; ah[j] = 0.f; }
  for (int i0 = beg; i0 < end; i0 += 8) {
    int ie = i0 + es;
    unsigned u = (ie < end) ? elist[ie] : 0u;   // u=0 -> s=0, nm=+0.0f
    int s = (int)(u & 0xffffu);
    float nm = __uint_as_float(u & 0xffff0000u);
    ushort8 xv = *(const ushort8*)&inX[s * 64 + cg * 8];
    ushort8 hv = *(const ushort8*)&inH[s * 64 + cg * 8];
#pragma unroll
    for (int j = 0; j < 8; ++j) {
      ax[j] += nm * bf2f(xv[j]);
      ah[j] += nm * bf2f(hv[j]);
    }
  }
#pragma unroll
  for (int mask = 8; mask <= 32; mask <<= 1) {
#pragma unroll
    for (int j = 0; j < 8; ++j) {
      ax[j] += __shfl_xor(ax[j], mask, 64);
      ah[j] += __shfl_xor(ah[j], mask, 64);
    }
  }
  if (es == 0) {
    const int o = n * 64 + cg * 8;
    ushort8 ox, oh;
    if (mode) {
      ushort8 bx8 = *(const ushort8*)&baseX[o];
      ushort8 bh8 = *(const ushort8*)&baseH[o];
#pragma unroll
      for (int j = 0; j < 8; ++j) {
        ox[j] = f2bf(2.f * ax[j] - bf2f(bx8[j]));
        oh[j] = f2bf(2.f * ah[j] - bf2f(bh8[j]));
      }
    } else {
#pragma unroll
      for (int j = 0; j < 8; ++j) { ox[j] = f2bf(ax[j]); oh[j] = f2bf(ah[j]); }
    }
    *(ushort8*)&outX[o] = ox;
    *(ushort8*)&outH[o] = oh;
  }
}

// MFMA gates v10: A staged in LDS with XOR-swizzled 16B granules
// (g' = g ^ (row&7)) -> coalesced global staging + conflict-free ds_read_b128.
// B from fragment-major Wb2 (contiguous 1KB wave loads). Block = 64 rows,
// wave = 16-col group, all 4 gates in-register.
__global__ __launch_bounds__(256, 3) void k_gates(
    const unsigned short* __restrict__ Xb, const unsigned short* __restrict__ Hb,
    const unsigned short* __restrict__ T1X, const unsigned short* __restrict__ T1H,
    const unsigned short* __restrict__ T2X, const unsigned short* __restrict__ T2H,
    const unsigned short* __restrict__ Wb2, const float* __restrict__ C,
    const float* __restrict__ bias, const float* __restrict__ wc,
    float* __restrict__ out) {
  __shared__ unsigned short A[6 * 64 * 64];  // 48 KB
  const int t = threadIdx.x;
  const int cw = t >> 6;
  const int l = t & 63;
  const int base = blockIdx.x * 64;
  const int lr = l & 15;

  // stage: 6 segs x 64 rows x 128B, swizzled granules
  const unsigned short* segp[6] = {Xb, T1X, T2X, Hb, T1H, T2H};
#pragma unroll
  for (int seg = 0; seg < 6; ++seg) {
    const unsigned short* sp = segp[seg];
#pragma unroll
    for (int half = 0; half < 2; ++half) {
      int r = half * 32 + (t >> 3);
      int n = base + r;
      int nc = (n < NN) ? n : NN - 1;
      int g = t & 7;
      ushort8 v = *(const ushort8*)&sp[nc * 64 + g * 8];
      *(ushort8*)&A[((seg * 64 + r) * 8 + (g ^ (r & 7))) * 8] = v;
    }
  }
  __syncthreads();

  f32x4 acc[4][4];              // [gate][row-group]
#pragma unroll
  for (int g = 0; g < 4; ++g)
#pragma unroll
    for (int rb = 0; rb < 4; ++rb) acc[g][rb] = (f32x4){0.f, 0.f, 0.f, 0.f};

  const int swz = (l >> 4) ^ (lr & 7);   // granule base ^ row-low-bits (half adds +4)
#pragma unroll
  for (int kc = 0; kc < 12; ++kc) {
    const int seg = kc >> 1;
    const int gp = ((kc & 1) * 4) ^ swz;  // (half*4 + (l>>4)) ^ (lr&7); half bit untouched by swz
    short8 a[4];
#pragma unroll
    for (int rb = 0; rb < 4; ++rb) {
      int row = rb * 16 + lr;
      a[rb] = *(const short8*)&A[((seg * 64 + row) * 8 + gp) * 8];
    }
#pragma unroll
    for (int g = 0; g < 4; ++g) {
      short8 b = *(const short8*)&Wb2[(((g * 12 + kc) * 4 + cw) << 9) + l * 8];
#pragma unroll
      for (int rb = 0; rb < 4; ++rb)
        acc[g][rb] = __builtin_amdgcn_mfma_f32_16x16x32_bf16(a[rb], b, acc[g][rb], 0, 0, 0);
    }
  }

  const int cc = cw * 16 + lr;
  const float bI = bias[cc],       bF = bias[64 + cc];
  const float bT = bias[128 + cc], bO = bias[192 + cc];
  const float wI = wc[cc], wF = wc[64 + cc], wO = wc[128 + cc];
#pragma unroll
  for (int rb = 0; rb < 4; ++rb) {
#pragma unroll
    for (int q = 0; q < 4; ++q) {
      int n = base + rb * 16 + (l >> 4) * 4 + q;
      if (n >= NN) continue;
      float cv = C[n * 64 + cc];
      float pI = acc[0][rb][q] + bI + wI * cv;
      float pF = acc[1][rb][q] + bF + wF * cv;
      float pT = acc[2][rb][q] + bT;
      float I = sigm(pI);
      float F = sigm(pF);
      float T = tanh_(pT);
      float Cn = F * cv + I * T;
      float pO = acc[3][rb][q] + bO + wO * Cn;
      float O = sigm(pO);
      out[n * 64 + cc] = O * tanh_(Cn);
      out[NN * 64 + n * 64 + cc] = Cn;
    }
  }
}

extern "C" void kernel_launch(void* const* d_in, const int* in_sizes, int n_in,
                              void* d_out, int out_size, void* d_ws, size_t ws_size,
                              hipStream_t stream) {
  const float* X  = (const float*)d_in[0];
  const int*   ei = (const int*)d_in[1];
  const float* ew = (const float*)d_in[2];
  const float* H  = (const float*)d_in[3];
  const float* C  = (const float*)d_in[4];
  const float* Wx = (const float*)d_in[5];
  const float* bx = (const float*)d_in[6];
  const float* Wh = (const float*)d_in[7];
  const float* bh = (const float*)d_in[8];
  const float* wc = (const float*)d_in[9];
  const float* bg = (const float*)d_in[10];
  float* out = (float*)d_out;
  float* ws = (float*)d_ws;

  const int* src = ei;
  const int* dst = ei + NE;
  float* dinv = ws + OFF_DEG;
  int* cnt = (int*)(ws + OFF_CNT);
  int* rowptr = (int*)(ws + OFF_ROWPTR);
  int* bsum = (int*)(ws + OFF_BSUM);
  unsigned short* Wb2 = (unsigned short*)(ws + OFF_WB);
  float* bias = ws + OFF_BIAS;
  unsigned* elist = (unsigned*)(ws + OFF_ELIST);
  unsigned short* histp = (unsigned short*)(ws + OFF_HISTP);
  unsigned short* colexc = (unsigned short*)(ws + OFF_COLEXC);
  float* degp = ws + OFF_DEGP;
  unsigned short* Xb  = (unsigned short*)(ws + OFF_XB);
  unsigned short* Hb  = (unsigned short*)(ws + OFF_HB);
  unsigned short* T1X = (unsigned short*)(ws + OFF_T1X);
  unsigned short* T1H = (unsigned short*)(ws + OFF_T1H);
  unsigned short* T2X = (unsigned short*)(ws + OFF_T2X);
  unsigned short* T2H = (unsigned short*)(ws + OFF_T2H);

  const int NBLK = (NN + 1023) / 1024;  // 49

  k_hd<<<512, 256, 0, stream>>>(src, dst, ew, histp, degp);
  k_col<<<(NN + 255) / 256, 256, 0, stream>>>(histp, colexc, degp, cnt, dinv);
  k_cw<<<CBLK + WBLK, 256, 0, stream>>>(X, H, Xb, Hb, Wx, Wh, bx, bh, bg, Wb2, bias);
  k_scanA<<<NBLK, 1024, 0, stream>>>(cnt, rowptr, bsum);
  k_scanB<<<1, 64, 0, stream>>>(bsum, rowptr, NBLK);
  k_scanC<<<NBLK, 1024, 0, stream>>>(rowptr, bsum);
  k_scat<<<256, 256, 0, stream>>>(src, dst, ew, dinv, rowptr, colexc, elist);
  k_prop<<<NN / 4, 256, 0, stream>>>(rowptr, elist, Xb, Hb, T1X, T1H,
                                     nullptr, nullptr, 0);
  k_prop<<<NN / 4, 256, 0, stream>>>(rowptr, elist, T1X, T1H, T2X, T2H,
                                     Xb, Hb, 1);
  k_gates<<<(NN + 63) / 64, 256, 0, stream>>>(Xb, Hb, T1X, T1H, T2X, T2H,
                                              Wb2, C, bias, wc, out);
}

// Round 14
// 213.311 us; speedup vs baseline: 2.1179x; 1.0340x over previous
//
#include <hip/hip_runtime.h>
#include <math.h>

#define NN 50000
#define NE 800000

typedef __attribute__((ext_vector_type(8))) short short8;
typedef __attribute__((ext_vector_type(8))) unsigned short ushort8;
typedef __attribute__((ext_vector_type(4))) float f32x4;

// workspace layout (offsets in 4-byte words) -- node-major tensors
#define OFF_DEG    0          // float[NN] -> dinv (written by k_colA)
#define OFF_BSUM   50000      // int[256] (in old CNT region -- 50000 words free)
#define OFF_ROWPTR 100000     // int[NN+1]
#define OFF_WB     200072     // ushort[192*512] fragment-major Wb2
#define OFF_BIAS   249224     // float[256]
#define OFF_ELIST  249480     // uint[NE]
#define OFF_XB     1849480    // ushort[NN*64] node-major, 1.6M words each
#define OFF_HB     3449480
#define OFF_T1X    5049480
#define OFF_T1H    6649480
#define OFF_T2X    8249480
#define OFF_T2H    9849480
// overlays (consumed before their hosts are written):
#define OFF_HISTP  5049480    // ushort[128][50000] over T1X+T1H
#define OFF_COLEXC 8249480    // ushort[128][50000] over T2X+T2H
#define OFF_DEGP   1849480    // float[64][50000] over XB+HB

#define DCH    128
#define DCHUNK 6250
#define DITER  25
#define SCH    64
#define SCHUNK 12500
#define SITER  49
#define CNBLK  196            // ceil(50000/256)

__device__ inline unsigned short f2bf(float f) {
  union { float f; unsigned u; } v; v.f = f;
  unsigned u = v.u;
  return (unsigned short)((u + 0x7FFFu + ((u >> 16) & 1u)) >> 16);
}
__device__ inline float bf2f(unsigned short u) {
  return __uint_as_float(((unsigned)u) << 16);
}
__device__ inline float sigm(float x) { return 1.f / (1.f + __expf(-x)); }
__device__ inline float tanh_(float x) { return 1.f - 2.f / (__expf(2.f * x) + 1.f); }

// fused histogram/degree, 512 blocks @ 50KB LDS
__global__ __launch_bounds__(256) void k_hd(
    const int* __restrict__ src, const int* __restrict__ dst,
    const float* __restrict__ w,
    unsigned short* __restrict__ histp, float* __restrict__ degp) {
  __shared__ unsigned lds[12500];
  const int t = threadIdx.x;
  const int bid = blockIdx.x;
  if (bid < 256) {
    const int c = bid >> 1, half = bid & 1, lo = half * 25000;
    for (int i = t; i < 12500; i += 256) lds[i] = 0u;
    __syncthreads();
    const int e0 = c * DCHUNK;
    for (int it = 0; it < DITER; ++it) {
      int o = it * 256 + t;
      if (o < DCHUNK) {
        int d = dst[e0 + o] - lo;
        if ((unsigned)d < 25000u)
          atomicAdd(&lds[d >> 1], (d & 1) ? 65536u : 1u);
      }
    }
    __syncthreads();
    unsigned* hw = (unsigned*)(histp + c * 50000 + lo);
    for (int i = t; i < 12500; i += 256) hw[i] = lds[i];
  } else {
    const int idx = bid - 256;
    const int c = idx >> 2, q = idx & 3, lo = q * 12500;
    float* ldsf = (float*)lds;
    for (int i = t; i < 12500; i += 256) ldsf[i] = 0.f;
    __syncthreads();
    const int e0 = c * SCHUNK;
    for (int it = 0; it < SITER; ++it) {
      int o = it * 256 + t;
      if (o < SCHUNK) {
        int s = src[e0 + o] - lo;
        if ((unsigned)s < 12500u) atomicAdd(&ldsf[s], w[e0 + o]);
      }
    }
    __syncthreads();
    float* dw = degp + c * 50000 + lo;
    for (int i = t; i < 12500; i += 256) dw[i] = ldsf[i];
  }
}

// fused: per-bin column sums -> colexc + dinv, then block-local inclusive
// scan -> rowptr[i+1] (local), block sum -> bsum
__global__ __launch_bounds__(256) void k_colA(
    const unsigned short* __restrict__ histp, unsigned short* __restrict__ colexc,
    const float* __restrict__ degp, int* __restrict__ rowptr,
    int* __restrict__ bsum, float* __restrict__ dinv) {
  __shared__ int wsum[4];
  const int t = threadIdx.x, lane = t & 63, w = t >> 6;
  const int bin = blockIdx.x * 256 + t;
  int acc = 0;
  if (bin < NN) {
#pragma unroll 8
    for (int b = 0; b < DCH; ++b) {
      unsigned short c = histp[b * 50000 + bin];
      colexc[b * 50000 + bin] = (unsigned short)acc;
      acc += c;
    }
    float dacc = 0.f;
#pragma unroll 8
    for (int b = 0; b < SCH; ++b) dacc += degp[b * 50000 + bin];
    dinv[bin] = (dacc > 0.f) ? rsqrtf(dacc) : 0.f;
  }
  int val = acc;
#pragma unroll
  for (int off = 1; off < 64; off <<= 1) {
    int u = __shfl_up(val, off, 64);
    if (lane >= off) val += u;
  }
  if (lane == 63) wsum[w] = val;
  __syncthreads();
  int wb = 0;
#pragma unroll
  for (int i = 0; i < 4; ++i) wb += (i < w) ? wsum[i] : 0;
  int incl = wb + val;
  if (bin < NN) rowptr[bin + 1] = incl;
  if (t == 255) bsum[blockIdx.x] = incl;
}

// single-block prefix over bsum[CNBLK] -> exclusive
__global__ __launch_bounds__(256) void k_scanB2(int* __restrict__ bsum,
                                                int* __restrict__ rowptr) {
  __shared__ int wsum[4];
  const int t = threadIdx.x, lane = t & 63, w = t >> 6;
  int v = (t < CNBLK) ? bsum[t] : 0;
  int val = v;
#pragma unroll
  for (int off = 1; off < 64; off <<= 1) {
    int u = __shfl_up(val, off, 64);
    if (lane >= off) val += u;
  }
  if (lane == 63) wsum[w] = val;
  __syncthreads();
  int wb = 0;
#pragma unroll
  for (int i = 0; i < 4; ++i) wb += (i < w) ? wsum[i] : 0;
  int incl = wb + val;
  if (t < CNBLK) bsum[t] = incl - v;  // exclusive
  if (t == 0) rowptr[0] = 0;
}

__global__ __launch_bounds__(256) void k_scanC2(int* __restrict__ rowptr,
                                                const int* __restrict__ bsum) {
  int i = blockIdx.x * 256 + threadIdx.x;
  if (i < NN) rowptr[i + 1] += bsum[blockIdx.x];
}

// cvt X,H -> bf16 node-major (8/thread) + Wb2 fragment-major + bias
#define CBLK 1563
#define WBLK 48
__global__ __launch_bounds__(256) void k_cw(
    const float* __restrict__ X, const float* __restrict__ H,
    unsigned short* __restrict__ Xb, unsigned short* __restrict__ Hb,
    const float* __restrict__ Wx, const float* __restrict__ Wh,
    const float* __restrict__ bx, const float* __restrict__ bh,
    const float* __restrict__ bg,
    unsigned short* __restrict__ Wb2, float* __restrict__ bias) {
  const int bid = blockIdx.x;
  const int t = threadIdx.x;
  if (bid < CBLK) {
    int i = (bid * 256 + t) * 8;
    if (i >= NN * 64) return;
    float4 x0 = *(const float4*)&X[i];
    float4 x1 = *(const float4*)&X[i + 4];
    float4 h0 = *(const float4*)&H[i];
    float4 h1 = *(const float4*)&H[i + 4];
    ushort8 xb, hb;
    xb[0] = f2bf(x0.x); xb[1] = f2bf(x0.y); xb[2] = f2bf(x0.z); xb[3] = f2bf(x0.w);
    xb[4] = f2bf(x1.x); xb[5] = f2bf(x1.y); xb[6] = f2bf(x1.z); xb[7] = f2bf(x1.w);
    hb[0] = f2bf(h0.x); hb[1] = f2bf(h0.y); hb[2] = f2bf(h0.z); hb[3] = f2bf(h0.w);
    hb[4] = f2bf(h1.x); hb[5] = f2bf(h1.y); hb[6] = f2bf(h1.z); hb[7] = f2bf(h1.w);
    *(ushort8*)&Xb[i] = xb;
    *(ushort8*)&Hb[i] = hb;
  } else {
    int idx = (bid - CBLK) * 256 + t;
    if (idx < 256) bias[idx] = bx[idx] + bh[idx] + bg[idx];
    if (idx >= 192 * 64) return;
    int word = idx >> 6, l = idx & 63;
    int cw = word & 3;
    int gk = word >> 2;
    int g = gk / 12, kc = gk - g * 12;
    int col = cw * 16 + (l & 15);
    int seg = kc >> 1;
    int kbase = (kc & 1) * 32 + (l >> 4) * 8;
    const float* Wsel = (seg < 3) ? Wx : Wh;
    int sch = (seg < 3) ? seg : seg - 3;
    ushort8 o8;
#pragma unroll
    for (int j = 0; j < 8; ++j) {
      float v = Wsel[((g * 3 + sch) * 64 + kbase + j) * 64 + col];
      o8[j] = f2bf(v);
    }
    *(ushort8*)&Wb2[idx * 8] = o8;
  }
}

// scatter, 256 blocks @ 50KB
__global__ __launch_bounds__(256) void k_scat(
    const int* __restrict__ src, const int* __restrict__ dst,
    const float* __restrict__ w, const float* __restrict__ dinv,
    const int* __restrict__ rowptr, const unsigned short* __restrict__ colexc,
    unsigned* __restrict__ elist) {
  __shared__ unsigned lds[12500];
  const int t = threadIdx.x, bid = blockIdx.x;
  const int c = bid >> 1, half = bid & 1, lo = half * 25000;
  for (int i = t; i < 12500; i += 256) lds[i] = 0u;
  __syncthreads();
  const int e0 = c * DCHUNK;
  for (int it = 0; it < DITER; ++it) {
    int o = it * 256 + t;
    if (o < DCHUNK) {
      int e = e0 + o;
      int d = dst[e];
      int dr = d - lo;
      if ((unsigned)dr < 25000u) {
        int s = src[e];
        float nm = -dinv[s] * w[e] * dinv[d];
        unsigned old = atomicAdd(&lds[dr >> 1], (dr & 1) ? 65536u : 1u);
        int rank = (dr & 1) ? (int)(old >> 16) : (int)(old & 0xffffu);
        int pos = rowptr[d] + (int)colexc[c * 50000 + d] + rank;
        elist[pos] = (((unsigned)f2bf(nm)) << 16) | (unsigned)s;
      }
    }
  }
}

// prop (node-major): wave per node; lane = (edge-slot es 0-7, ch-group cg 0-7)
__global__ __launch_bounds__(256) void k_prop(
    const int* __restrict__ rowptr, const unsigned* __restrict__ elist,
    const unsigned short* __restrict__ inX, const unsigned short* __restrict__ inH,
    unsigned short* __restrict__ outX, unsigned short* __restrict__ outH,
    const unsigned short* __restrict__ baseX, const unsigned short* __restrict__ baseH,
    int mode) {
  const int n = blockIdx.x * 4 + (threadIdx.x >> 6);
  const int l = threadIdx.x & 63;
  const int es = l >> 3;
  const int cg = l & 7;
  if (n >= NN) return;
  const int beg = rowptr[n], end = rowptr[n + 1];
  float ax[8], ah[8];
#pragma unroll
  for (int j = 0; j < 8; ++j) { ax[j] = 0.f; ah[j] = 0.f; }
  for (int i0 = beg; i0 < end; i0 += 8) {
    int ie = i0 + es;
    unsigned u = (ie < end) ? elist[ie] : 0u;
    int s = (int)(u & 0xffffu);
    float nm = __uint_as_float(u & 0xffff0000u);
    ushort8 xv = *(const ushort8*)&inX[s * 64 + cg * 8];
    ushort8 hv = *(const ushort8*)&inH[s * 64 + cg * 8];
#pragma unroll
    for (int j = 0; j < 8; ++j) {
      ax[j] += nm * bf2f(xv[j]);
      ah[j] += nm * bf2f(hv[j]);
    }
  }
#pragma unroll
  for (int mask = 8; mask <= 32; mask <<= 1) {
#pragma unroll
    for (int j = 0; j < 8; ++j) {
      ax[j] += __shfl_xor(ax[j], mask, 64);
      ah[j] += __shfl_xor(ah[j], mask, 64);
    }
  }
  if (es == 0) {
    const int o = n * 64 + cg * 8;
    ushort8 ox, oh;
    if (mode) {
      ushort8 bx8 = *(const ushort8*)&baseX[o];
      ushort8 bh8 = *(const ushort8*)&baseH[o];
#pragma unroll
      for (int j = 0; j < 8; ++j) {
        ox[j] = f2bf(2.f * ax[j] - bf2f(bx8[j]));
        oh[j] = f2bf(2.f * ah[j] - bf2f(bh8[j]));
      }
    } else {
#pragma unroll
      for (int j = 0; j < 8; ++j) { ox[j] = f2bf(ax[j]); oh[j] = f2bf(ah[j]); }
    }
    *(ushort8*)&outX[o] = ox;
    *(ushort8*)&outH[o] = oh;
  }
}

// MFMA gates v11: 32-row tiles (24KB LDS -> 5-6 blocks/CU), batched reg-staged
// swizzled LDS, fragment-major B, C prefetched, epilogue in registers.
__global__ __launch_bounds__(256, 4) void k_gates(
    const unsigned short* __restrict__ Xb, const unsigned short* __restrict__ Hb,
    const unsigned short* __restrict__ T1X, const unsigned short* __restrict__ T1H,
    const unsigned short* __restrict__ T2X, const unsigned short* __restrict__ T2H,
    const unsigned short* __restrict__ Wb2, const float* __restrict__ C,
    const float* __restrict__ bias, const float* __restrict__ wc,
    float* __restrict__ out) {
  __shared__ unsigned short A[6 * 32 * 64];  // 24 KB
  const int t = threadIdx.x;
  const int cw = t >> 6;
  const int l = t & 63;
  const int base = blockIdx.x * 32;
  const int lr = l & 15;
  const int cc = cw * 16 + lr;

  // C prefetch (8 values) -- issued before staging so HBM latency overlaps
  float cpre[2][4];
#pragma unroll
  for (int rb = 0; rb < 2; ++rb)
#pragma unroll
    for (int q = 0; q < 4; ++q) {
      int n = base + rb * 16 + (l >> 4) * 4 + q;
      int nc = (n < NN) ? n : NN - 1;
      cpre[rb][q] = C[nc * 64 + cc];
    }

  // stage: 6 segs x 32 rows x 128B; batched loads then swizzled writes
  const unsigned short* segp[6] = {Xb, T1X, T2X, Hb, T1H, T2H};
  {
    const int r = t >> 3, g0 = t & 7;
    const int gsw = g0 ^ (r & 7);
    int n = base + r;
    int nc = (n < NN) ? n : NN - 1;
    ushort8 st[6];
#pragma unroll
    for (int seg = 0; seg < 6; ++seg)
      st[seg] = *(const ushort8*)&segp[seg][nc * 64 + gsw * 8];
#pragma unroll
    for (int seg = 0; seg < 6; ++seg)
      *(ushort8*)&A[(seg * 256 + t) * 8] = st[seg];
  }
  __syncthreads();

  f32x4 acc[4][2];              // [gate][row-group]
#pragma unroll
  for (int g = 0; g < 4; ++g) {
    acc[g][0] = (f32x4){0.f, 0.f, 0.f, 0.f};
    acc[g][1] = (f32x4){0.f, 0.f, 0.f, 0.f};
  }

#pragma unroll
  for (int kc = 0; kc < 12; ++kc) {
    const int seg = kc >> 1;
    const int slot = ((kc & 1) * 4 + (l >> 4)) ^ (lr & 7);
    short8 a[2];
#pragma unroll
    for (int rb = 0; rb < 2; ++rb) {
      int row = rb * 16 + lr;
      a[rb] = *(const short8*)&A[((seg * 32 + row) * 8 + slot) * 8];
    }
#pragma unroll
    for (int g = 0; g < 4; ++g) {
      short8 b = *(const short8*)&Wb2[(((g * 12 + kc) * 4 + cw) << 9) + l * 8];
      acc[g][0] = __builtin_amdgcn_mfma_f32_16x16x32_bf16(a[0], b, acc[g][0], 0, 0, 0);
      acc[g][1] = __builtin_amdgcn_mfma_f32_16x16x32_bf16(a[1], b, acc[g][1], 0, 0, 0);
    }
  }

  const float bI = bias[cc],       bF = bias[64 + cc];
  const float bT = bias[128 + cc], bO = bias[192 + cc];
  const float wI = wc[cc], wF = wc[64 + cc], wO = wc[128 + cc];
#pragma unroll
  for (int rb = 0; rb < 2; ++rb) {
#pragma unroll
    for (int q = 0; q < 4; ++q) {
      int n = base + rb * 16 + (l >> 4) * 4 + q;
      if (n >= NN) continue;
      float cv = cpre[rb][q];
      float pI = acc[0][rb][q] + bI + wI * cv;
      float pF = acc[1][rb][q] + bF + wF * cv;
      float pT = acc[2][rb][q] + bT;
      float I = sigm(pI);
      float F = sigm(pF);
      float T = tanh_(pT);
      float Cn = F * cv + I * T;
      float pO = acc[3][rb][q] + bO + wO * Cn;
      float O = sigm(pO);
      out[n * 64 + cc] = O * tanh_(Cn);
      out[NN * 64 + n * 64 + cc] = Cn;
    }
  }
}

extern "C" void kernel_launch(void* const* d_in, const int* in_sizes, int n_in,
                              void* d_out, int out_size, void* d_ws, size_t ws_size,
                              hipStream_t stream) {
  const float* X  = (const float*)d_in[0];
  const int*   ei = (const int*)d_in[1];
  const float* ew = (const float*)d_in[2];
  const float* H  = (const float*)d_in[3];
  const float* C  = (const float*)d_in[4];
  const float* Wx = (const float*)d_in[5];
  const float* bx = (const float*)d_in[6];
  const float* Wh = (const float*)d_in[7];
  const float* bh = (const float*)d_in[8];
  const float* wc = (const float*)d_in[9];
  const float* bg = (const float*)d_in[10];
  float* out = (float*)d_out;
  float* ws = (float*)d_ws;

  const int* src = ei;
  const int* dst = ei + NE;
  float* dinv = ws + OFF_DEG;
  int* bsum = (int*)(ws + OFF_BSUM);
  int* rowptr = (int*)(ws + OFF_ROWPTR);
  unsigned short* Wb2 = (unsigned short*)(ws + OFF_WB);
  float* bias = ws + OFF_BIAS;
  unsigned* elist = (unsigned*)(ws + OFF_ELIST);
  unsigned short* histp = (unsigned short*)(ws + OFF_HISTP);
  unsigned short* colexc = (unsigned short*)(ws + OFF_COLEXC);
  float* degp = ws + OFF_DEGP;
  unsigned short* Xb  = (unsigned short*)(ws + OFF_XB);
  unsigned short* Hb  = (unsigned short*)(ws + OFF_HB);
  unsigned short* T1X = (unsigned short*)(ws + OFF_T1X);
  unsigned short* T1H = (unsigned short*)(ws + OFF_T1H);
  unsigned short* T2X = (unsigned short*)(ws + OFF_T2X);
  unsigned short* T2H = (unsigned short*)(ws + OFF_T2H);

  k_hd<<<512, 256, 0, stream>>>(src, dst, ew, histp, degp);
  k_colA<<<CNBLK, 256, 0, stream>>>(histp, colexc, degp, rowptr, bsum, dinv);
  k_cw<<<CBLK + WBLK, 256, 0, stream>>>(X, H, Xb, Hb, Wx, Wh, bx, bh, bg, Wb2, bias);
  k_scanB2<<<1, 256, 0, stream>>>(bsum, rowptr);
  k_scanC2<<<CNBLK, 256, 0, stream>>>(rowptr, bsum);
  k_scat<<<256, 256, 0, stream>>>(src, dst, ew, dinv, rowptr, colexc, elist);
  k_prop<<<NN / 4, 256, 0, stream>>>(rowptr, elist, Xb, Hb, T1X, T1H,
                                     nullptr, nullptr, 0);
  k_prop<<<NN / 4, 256, 0, stream>>>(rowptr, elist, T1X, T1H, T2X, T2H,
                                     Xb, Hb, 1);
  k_gates<<<(NN + 31) / 32, 256, 0, stream>>>(Xb, Hb, T1X, T1H, T2X, T2H,
                                              Wb2, C, bias, wc, out);
}